// Round 6
// baseline (1042.418 us; speedup 1.0000x reference)
//
#include <hip/hip_runtime.h>

typedef _Float16 f16x8 __attribute__((ext_vector_type(8)));
typedef _Float16 f16x4 __attribute__((ext_vector_type(4)));
typedef float    f32x4 __attribute__((ext_vector_type(4)));

#define BM 128
#define BN 128
#define BK 32

// async global->LDS, 16B per lane. LDS dst must be wave-uniform base + lane*16.
__device__ __forceinline__ void gld16(const void* g, void* l) {
  __builtin_amdgcn_global_load_lds(
      (__attribute__((address_space(1))) void*)const_cast<void*>(g),
      (__attribute__((address_space(3))) void*)l, 16, 0, 0);
}

// Branchless activations from ONE native exp (e2 = e*e), fast rcp divides.
// relu / sigmoid / tanh / leaky(0.1) / selu, then min(out, cap).
__device__ __forceinline__ float act_clip(int f, float v, float cap) {
  const float sc = 1.0507009873554805f, al = 1.6732632423543772f;
  const float av = fabsf(v);
  const float e  = __expf(-av);
  const float e2 = e * e;
  const bool  pos = (v >= 0.0f);

  const float r1 = __builtin_amdgcn_rcpf(1.0f + e);
  const float sig = pos ? r1 : e * r1;
  float th = (1.0f - e2) * __builtin_amdgcn_rcpf(1.0f + e2);
  th = pos ? th : -th;
  const float rel = fmaxf(v, 0.0f);
  const float lk  = pos ? v : 0.1f * v;
  const float sel = pos ? sc * v : sc * al * (e - 1.0f);

  float out = rel;
  out = (f == 1) ? sig : out;
  out = (f == 2) ? th  : out;
  out = (f == 3) ? lk  : out;
  out = (f == 4) ? sel : out;
  return fminf(out, cap);
}

// C[M,N] = A[M,K] @ W[N,K]^T + bias, per-column activation+clip.
// A: f16 hi/lo planes, staged to double-buffered LDS via global_load_lds
//    (DMA for iter k+1 issued at top of iter k -> latency hidden under MFMA).
// W: PRE-PACKED in MFMA fragment order [plane][N/16][K/32][lane 64][8 f16];
//    loaded straight to VGPRs with coalesced dwordx4 -> no LDS, no barrier dep.
// fp32 accumulate via 3 MFMA products (hh, hl, lh) -> ~2^-22 effective input.
// NOTE: no min-waves in __launch_bounds__ -- forcing 5 waves/EU spilled to
// scratch (2.5 GB/dispatch HBM, 4x slower: round-4 evidence).
__global__ __launch_bounds__(256) void gemm_bpack_act(
    const _Float16* __restrict__ Ahi, const _Float16* __restrict__ Alo,
    const _Float16* __restrict__ Bpk,
    const float* __restrict__ bias, const int* __restrict__ fid,
    const float* __restrict__ cap, int N, int K, int nCol, int nRow,
    _Float16* __restrict__ Ohi, _Float16* __restrict__ Olo,
    float* __restrict__ Ofin)
{
  __shared__ _Float16 sA[2][2][BM * BK];   // [hi/lo][dbuf][swizzled granules]

  const int tid  = threadIdx.x;
  const int lane = tid & 63;
  const int wave = tid >> 6;
  const int wm = (wave >> 1) * 64;
  const int wn = (wave & 1) * 64;
  const int ml = lane & 15;
  const int q  = lane >> 4;

  int rb, cb;
  if ((nRow & 7) == 0) {   // XCD swizzle: one XCD runs all col-blocks of a row-group
    const int id = blockIdx.x;
    const int xcd = id & 7, slot = id >> 3;
    cb = slot % nCol;
    rb = (slot / nCol) * 8 + xcd;
  } else {
    cb = blockIdx.x % nCol;
    rb = blockIdx.x / nCol;
  }

  const long row0 = (long)rb * BM;
  const int  col0 = cb * BN;

  // A staging: thread covers rows (tid>>2), (tid>>2)+64; XOR-swizzled k-chunk.
  const int srow = tid >> 2;
  const int scol = ((tid & 3) ^ (srow & 3) ^ ((srow >> 2) & 3)) * 8;
  const _Float16* gAh = Ahi + (row0 + srow) * (long)K + scol;
  const _Float16* gAl = Alo + (row0 + srow) * (long)K + scol;

  // fragment-read swizzle term (loop-invariant per lane)
  const int sw = (q ^ (ml & 3) ^ (ml >> 2)) * 8;

  // packed-B addressing: frag (jt, kt) is 512 f16 = 64 lanes x 8, contiguous.
  const int  KT  = K >> 5;
  const int  jt0 = (col0 + wn) >> 4;
  const long planeB = (long)N * K;           // lo-plane offset in elems
  const _Float16* bb = Bpk + ((long)jt0 * KT) * 512 + (long)lane * 8;

  f32x4 acc[4][4] = {};

  // prologue: stage A(0) into buf 0
  gld16(gAh,                &sA[0][0][tid * 8]);
  gld16(gAh + (long)64 * K, &sA[0][0][64 * BK + tid * 8]);
  gld16(gAl,                &sA[1][0][tid * 8]);
  gld16(gAl + (long)64 * K, &sA[1][0][64 * BK + tid * 8]);
  __syncthreads();

  for (int kt = 0; kt < KT; ++kt) {
    const int cur = kt & 1;

    // B fragments for THIS iter first (so their vmcnt wait doesn't imply
    // waiting on the later-issued A-DMA).
    f16x8 bh[4], bl[4];
#pragma unroll
    for (int j = 0; j < 4; j++) {
      const long fo = ((long)j * KT + kt) * 512;
      bh[j] = *(const f16x8*)(bb + fo);
      bl[j] = *(const f16x8*)(bb + fo + planeB);
    }

    // A-DMA for NEXT iter into the other buffer (latency hides under MFMA)
    if (kt + 1 < KT) {
      const int nxt = cur ^ 1;
      const long ko = (long)(kt + 1) * BK;
      gld16(gAh + ko,                &sA[0][nxt][tid * 8]);
      gld16(gAh + (long)64 * K + ko, &sA[0][nxt][64 * BK + tid * 8]);
      gld16(gAl + ko,                &sA[1][nxt][tid * 8]);
      gld16(gAl + (long)64 * K + ko, &sA[1][nxt][64 * BK + tid * 8]);
    }

    f16x8 ah[4], al[4];
#pragma unroll
    for (int i = 0; i < 4; i++) {
      ah[i] = *(const f16x8*)&sA[0][cur][(wm + i * 16 + ml) * BK + sw];
      al[i] = *(const f16x8*)&sA[1][cur][(wm + i * 16 + ml) * BK + sw];
    }

#pragma unroll
    for (int i = 0; i < 4; i++)
#pragma unroll
      for (int j = 0; j < 4; j++) {
        acc[i][j] = __builtin_amdgcn_mfma_f32_16x16x32_f16(ah[i], bh[j], acc[i][j], 0, 0, 0);
        acc[i][j] = __builtin_amdgcn_mfma_f32_16x16x32_f16(ah[i], bl[j], acc[i][j], 0, 0, 0);
        acc[i][j] = __builtin_amdgcn_mfma_f32_16x16x32_f16(al[i], bh[j], acc[i][j], 0, 0, 0);
      }

    // barrier: everyone done reading sA[.][cur]; drains vmcnt -> A(kt+1) landed.
    __syncthreads();
  }

  // epilogue: C/D layout col = lane&15, row = (lane>>4)*4 + reg
#pragma unroll
  for (int j = 0; j < 4; j++) {
    const int col = col0 + wn + j * 16 + ml;
    const float bj = bias[col];
    const int   fj = fid[col];
    const float cj = cap[col];
#pragma unroll
    for (int i = 0; i < 4; i++) {
      const long rbase = row0 + wm + i * 16 + q * 4;
#pragma unroll
      for (int r = 0; r < 4; r++) {
        float v = act_clip(fj, acc[i][j][r] + bj, cj);
        const long idx = (rbase + r) * (long)N + col;
        if (Ofin) {
          Ofin[idx] = v;
        } else {
          _Float16 h = (_Float16)v;
          Ohi[idx] = h;
          Olo[idx] = (_Float16)(v - (float)h);
        }
      }
    }
  }
}

// fp32 -> (hi,lo) f16 split planes, 4 elems/thread (activations/input)
__global__ void split_f32(const float* __restrict__ x, _Float16* __restrict__ hi,
                          _Float16* __restrict__ lo, long n)
{
  long i = ((long)blockIdx.x * 256 + threadIdx.x) * 4;
  if (i >= n) return;
  float4 v = *(const float4*)(x + i);
  f16x4 h, l;
  h[0] = (_Float16)v.x; l[0] = (_Float16)(v.x - (float)h[0]);
  h[1] = (_Float16)v.y; l[1] = (_Float16)(v.y - (float)h[1]);
  h[2] = (_Float16)v.z; l[2] = (_Float16)(v.z - (float)h[2]);
  h[3] = (_Float16)v.w; l[3] = (_Float16)(v.w - (float)h[3]);
  *(f16x4*)(hi + i) = h;
  *(f16x4*)(lo + i) = l;
}

// fp32 W[N,K] -> packed hi/lo f16 in MFMA-fragment order:
//   out[plane][jt = n/16][kt = k/32][lane 64][8],
//   element(lane l, e) = W[jt*16 + (l&15)][kt*32 + (l>>4)*8 + e].
__global__ void pack_w(const float* __restrict__ W, _Float16* __restrict__ out,
                       int N, int K)
{
  const long total = (long)(N >> 4) * (K >> 5) * 64;   // fragment-lane count
  long t = (long)blockIdx.x * 256 + threadIdx.x;
  if (t >= total) return;
  const int  l  = (int)(t & 63);
  const long fk = t >> 6;                   // jt*(K/32) + kt
  const int  KT = K >> 5;
  const int  kt = (int)(fk % KT);
  const int  jt = (int)(fk / KT);
  const float* src = W + (long)(jt * 16 + (l & 15)) * K + kt * 32 + (l >> 4) * 8;
  _Float16* dh = out + fk * 512 + (long)l * 8;
  _Float16* dl = dh + (long)N * K;
#pragma unroll
  for (int e = 0; e < 8; e++) {
    float v = src[e];
    _Float16 h = (_Float16)v;
    dh[e] = h;
    dl[e] = (_Float16)(v - (float)h);
  }
}

extern "C" void kernel_launch(void* const* d_in, const int* in_sizes, int n_in,
                              void* d_out, int out_size, void* d_ws, size_t ws_size,
                              hipStream_t stream)
{
  const float* input = (const float*)d_in[0];
  const float* W_in  = (const float*)d_in[1];
  const float* b_in  = (const float*)d_in[2];
  const float* W_h   = (const float*)d_in[3];
  const float* b_h   = (const float*)d_in[4];
  const float* W_out = (const float*)d_in[5];
  const float* b_out = (const float*)d_in[6];
  const float* m_in  = (const float*)d_in[7];
  const float* m_h   = (const float*)d_in[8];
  const float* m_out = (const float*)d_in[9];
  const int* fid_in  = (const int*)d_in[10];
  const int* fid_h   = (const int*)d_in[11];
  const int* fid_out = (const int*)d_in[12];

  const int X     = in_sizes[2];                 // 512
  const int D_IN  = in_sizes[1] / X;             // 512
  const int Z     = in_sizes[3] / (X * X);       // 4
  const int D_OUT = in_sizes[6];                 // 128
  const long B    = (long)in_sizes[0] / D_IN;    // 65536

  // workspace: packed weights (hi+lo interleaved per layer: 2*n elems each),
  // then ping-pong activation hi/lo planes.
  const long n_in_w  = (long)X * D_IN;
  const long n_h_w   = (long)X * X;
  const long n_out_w = (long)D_OUT * X;
  const long w_elems = n_in_w + Z * n_h_w + n_out_w;

  _Float16* Wp_in  = (_Float16*)d_ws;                 // 2*n_in_w
  _Float16* Wp_h0  = Wp_in + 2 * n_in_w;              // Z consecutive, 2*n_h_w each
  _Float16* Wp_out = Wp_h0 + Z * 2 * n_h_w;           // 2*n_out_w
  char* actbase = (char*)(Wp_out + 2 * n_out_w);

  size_t wbytes = 4 * (size_t)w_elems;
  size_t avail  = ws_size > wbytes ? ws_size - wbytes : 0;
  long R = (long)(avail / (8 * (size_t)X));
  R = (R / BM) * BM;
  if (R > B) R = B;
  if (R < BM) R = BM;

  _Float16* bufhi[2];
  _Float16* buflo[2];
  bufhi[0] = (_Float16*)actbase;
  buflo[0] = bufhi[0] + R * (long)X;
  bufhi[1] = buflo[0] + R * (long)X;
  buflo[1] = bufhi[1] + R * (long)X;

  // pack weights (fragment order, hi/lo planes) once per call
  {
    long t0 = n_in_w / 8, t1 = n_h_w / 8, t2 = n_out_w / 8;
    pack_w<<<(int)((t0 + 255) / 256), 256, 0, stream>>>(W_in, Wp_in, X, D_IN);
    for (int i = 0; i < Z; i++)
      pack_w<<<(int)((t1 + 255) / 256), 256, 0, stream>>>(
          W_h + (long)i * n_h_w, Wp_h0 + (long)i * 2 * n_h_w, X, X);
    pack_w<<<(int)((t2 + 255) / 256), 256, 0, stream>>>(W_out, Wp_out, D_OUT, X);
  }

  for (long r0 = 0; r0 < B; r0 += R) {
    const long rows = (B - r0 < R) ? (B - r0) : R;

    {
      long n = rows * (long)D_IN;
      split_f32<<<(int)((n / 4 + 255) / 256), 256, 0, stream>>>(input + r0 * D_IN, bufhi[0], buflo[0], n);
    }

    const int nRow  = (int)(rows / BM);
    const int nColH = X / BN;
    dim3 gridH((unsigned)(nRow * nColH));
    gemm_bpack_act<<<gridH, 256, 0, stream>>>(bufhi[0], buflo[0], Wp_in,
        b_in, fid_in, m_in, X, D_IN, nColH, nRow, bufhi[1], buflo[1], nullptr);
    int cur = 1;
    for (int i = 0; i < Z; i++) {
      gemm_bpack_act<<<gridH, 256, 0, stream>>>(bufhi[cur], buflo[cur],
          Wp_h0 + (long)i * 2 * n_h_w,
          b_h + (long)i * X, fid_h + (long)i * X, m_h + (long)i * X, X, X,
          nColH, nRow, bufhi[1 - cur], buflo[1 - cur], nullptr);
      cur ^= 1;
    }
    const int nColO = D_OUT / BN;
    dim3 gridO((unsigned)(nRow * nColO));
    gemm_bpack_act<<<gridO, 256, 0, stream>>>(bufhi[cur], buflo[cur], Wp_out,
        b_out, fid_out, m_out, D_OUT, X,
        nColO, nRow, nullptr, nullptr, (float*)d_out + r0 * (long)D_OUT);
  }
}

// Round 7
// 1031.653 us; speedup vs baseline: 1.0104x; 1.0104x over previous
//
#include <hip/hip_runtime.h>

typedef _Float16 f16x8 __attribute__((ext_vector_type(8)));
typedef float    f32x4 __attribute__((ext_vector_type(4)));

#define BM 128
#define BN 128
#define BK 32

// Branchless activations from ONE native exp (e2 = e*e), fast rcp divides.
__device__ __forceinline__ float act_clip(int f, float v, float cap) {
  const float sc = 1.0507009873554805f, al = 1.6732632423543772f;
  const float av = fabsf(v);
  const float e  = __expf(-av);
  const float e2 = e * e;
  const bool  pos = (v >= 0.0f);

  const float r1 = __builtin_amdgcn_rcpf(1.0f + e);
  const float sig = pos ? r1 : e * r1;
  float th = (1.0f - e2) * __builtin_amdgcn_rcpf(1.0f + e2);
  th = pos ? th : -th;
  const float rel = fmaxf(v, 0.0f);
  const float lk  = pos ? v : 0.1f * v;
  const float sel = pos ? sc * v : sc * al * (e - 1.0f);

  float out = rel;
  out = (f == 1) ? sig : out;
  out = (f == 2) ? th  : out;
  out = (f == 3) ? lk  : out;
  out = (f == 4) ? sel : out;
  return fminf(out, cap);
}

// Barrier-free GEMM: C[M,N] = A @ W^T + bias, activation+clip fused.
// BOTH operands pre-packed in MFMA fragment order:
//   frag(d0t, kt) = 512 f16 contiguous; lane l holds dim0 = d0t*16+(l&15),
//   k = kt*32+(l>>4)*8 .. +8. lo-plane at +planeA / +planeB.
// K-loop: fully-coalesced 1KB global loads -> VGPR, 2-deep register pipeline,
// NO LDS, NO __syncthreads (the round-5 structure lost ~35% to barrier
// drains; round-6 showed per-wave B loads are fine when A stays off L2's
// back -- here A-frags are read once per wave-pair from L2, XCD-swizzled).
// Epilogue: per-wave PRIVATE LDS transpose (no barrier) to emit the next
// layer's packed-A layout, or direct f32 store for the final layer.
__global__ __launch_bounds__(256) void gemm_pk_act(
    const _Float16* __restrict__ Apk, long planeA,
    const _Float16* __restrict__ Bpk,
    const float* __restrict__ bias, const int* __restrict__ fid,
    const float* __restrict__ cap, int N, int K, int nCol, int nRow,
    _Float16* __restrict__ Opk, long planeO,
    float* __restrict__ Ofin)
{
  __shared__ float sC[4][64][36];   // per-wave private transpose scratch

  const int tid  = threadIdx.x;
  const int lane = tid & 63;
  const int wave = tid >> 6;
  const int wm = (wave >> 1) * 64;
  const int wn = (wave & 1) * 64;
  const int ml = lane & 15;
  const int q  = lane >> 4;

  int rb, cb;
  if ((nRow & 7) == 0) {   // XCD swizzle: one XCD runs all col-blocks of a row-group
    const int id = blockIdx.x;
    const int xcd = id & 7, slot = id >> 3;
    cb = slot % nCol;
    rb = (slot / nCol) * 8 + xcd;
  } else {
    cb = blockIdx.x % nCol;
    rb = blockIdx.x / nCol;
  }

  const long row0 = (long)rb * BM;
  const int  col0 = cb * BN;
  const int  KT   = K >> 5;

  const long planeB = (long)N * K;
  const _Float16* ap = Apk + (((long)(row0 + wm) >> 4) * KT) * 512 + (long)lane * 8;
  const _Float16* bp = Bpk + (((long)(col0 + wn) >> 4) * KT) * 512 + (long)lane * 8;

  f32x4 acc[4][4] = {};
  f16x8 af[2][8], bf[2][8];   // [buf][hi 0..3 | lo 4..7]

#define LOADF(buf, kt_)                                              \
  {                                                                  \
    _Pragma("unroll") for (int i = 0; i < 4; i++) {                  \
      const long o = ((long)i * KT + (kt_)) * 512;                   \
      af[buf][i]     = *(const f16x8*)(ap + o);                      \
      af[buf][4 + i] = *(const f16x8*)(ap + o + planeA);             \
      bf[buf][i]     = *(const f16x8*)(bp + o);                      \
      bf[buf][4 + i] = *(const f16x8*)(bp + o + planeB);             \
    }                                                                \
  }

#define MFMA48(buf)                                                                             \
  {                                                                                             \
    _Pragma("unroll") for (int i = 0; i < 4; i++)                                               \
      _Pragma("unroll") for (int j = 0; j < 4; j++) {                                           \
        acc[i][j] = __builtin_amdgcn_mfma_f32_16x16x32_f16(af[buf][i],     bf[buf][j],     acc[i][j], 0, 0, 0); \
        acc[i][j] = __builtin_amdgcn_mfma_f32_16x16x32_f16(af[buf][i],     bf[buf][4 + j], acc[i][j], 0, 0, 0); \
        acc[i][j] = __builtin_amdgcn_mfma_f32_16x16x32_f16(af[buf][4 + i], bf[buf][j],     acc[i][j], 0, 0, 0); \
      }                                                                                         \
  }

  LOADF(0, 0)
  for (int kt = 0; kt < KT; kt += 2) {   // KT is even (K multiple of 64)
    LOADF(1, kt + 1)
    MFMA48(0)
    if (kt + 2 < KT) LOADF(0, kt + 2)
    MFMA48(1)
  }

  if (Ofin) {
    // final layer: direct f32 store, C/D layout col=lane&15, row=q*4+reg
#pragma unroll
    for (int j = 0; j < 4; j++) {
      const int col = col0 + wn + j * 16 + ml;
      const float bj = bias[col];
      const int   fj = fid[col];
      const float cj = cap[col];
#pragma unroll
      for (int i = 0; i < 4; i++) {
        const long rbase = row0 + wm + i * 16 + q * 4;
#pragma unroll
        for (int r = 0; r < 4; r++)
          Ofin[(rbase + r) * (long)N + col] = act_clip(fj, acc[i][j][r] + bj, cj);
      }
    }
  } else {
    // intermediate: repack into next layer's A-fragment layout via private LDS
    const int KTn = N >> 5;
#pragma unroll
    for (int h = 0; h < 2; h++) {        // two 32-col halves
#pragma unroll
      for (int jj = 0; jj < 2; jj++) {
        const int j = 2 * h + jj;
        const int col = col0 + wn + j * 16 + ml;
        const float bj = bias[col];
        const int   fj = fid[col];
        const float cj = cap[col];
#pragma unroll
        for (int i = 0; i < 4; i++)
#pragma unroll
          for (int r = 0; r < 4; r++)
            sC[wave][i * 16 + q * 4 + r][jj * 16 + ml] =
                act_clip(fj, acc[i][j][r] + bj, cj);
      }
      // same-wave LDS dependency only -> compiler inserts lgkmcnt, no barrier
      const long kt_g = ((col0 + wn) >> 5) + h;
#pragma unroll
      for (int i = 0; i < 4; i++) {
        const float4 v0 = *(const float4*)&sC[wave][i * 16 + ml][q * 8];
        const float4 v1 = *(const float4*)&sC[wave][i * 16 + ml][q * 8 + 4];
        f16x8 hh;
        f16x8 ll;
        const float vv[8] = {v0.x, v0.y, v0.z, v0.w, v1.x, v1.y, v1.z, v1.w};
#pragma unroll
        for (int e = 0; e < 8; e++) {
          _Float16 hv = (_Float16)vv[e];
          hh[e] = hv;
          ll[e] = (_Float16)(vv[e] - (float)hv);
        }
        const long mt_g = ((row0 + wm) >> 4) + i;
        _Float16* dh = Opk + ((long)mt_g * KTn + kt_g) * 512 + (long)lane * 8;
        *(f16x8*)dh = hh;
        *(f16x8*)(dh + planeO) = ll;
      }
    }
  }
#undef LOADF
#undef MFMA48
}

// fp32 W[N,K] -> packed hi/lo f16 in MFMA-fragment order (HW-verified round 6).
__global__ void pack_w(const float* __restrict__ W, _Float16* __restrict__ out,
                       int N, int K)
{
  const long total = (long)(N >> 4) * (K >> 5) * 64;
  long t = (long)blockIdx.x * 256 + threadIdx.x;
  if (t >= total) return;
  const int  l  = (int)(t & 63);
  const long fk = t >> 6;
  const int  KT = K >> 5;
  const int  kt = (int)(fk % KT);
  const int  jt = (int)(fk / KT);
  const float* src = W + (long)(jt * 16 + (l & 15)) * K + kt * 32 + (l >> 4) * 8;
  _Float16* dh = out + fk * 512 + (long)l * 8;
  _Float16* dl = dh + (long)N * K;
#pragma unroll
  for (int e = 0; e < 8; e++) {
    float v = src[e];
    _Float16 h = (_Float16)v;
    dh[e] = h;
    dl[e] = (_Float16)(v - (float)h);
  }
}

// fp32 x[rows,K] -> packed hi/lo A-fragment layout (layer-0 input)
__global__ void pack_a(const float* __restrict__ x, _Float16* __restrict__ out,
                       long planeO, int K, long total)
{
  long t = (long)blockIdx.x * 256 + threadIdx.x;
  if (t >= total) return;
  const int  l  = (int)(t & 63);
  const long fk = t >> 6;                  // mt*KT + kt
  const int  KT = K >> 5;
  const int  kt = (int)(fk % KT);
  const long mt = fk / KT;
  const float* src = x + (mt * 16 + (l & 15)) * (long)K + kt * 32 + (l >> 4) * 8;
  _Float16* dh = out + fk * 512 + (long)l * 8;
  _Float16* dl = dh + planeO;
#pragma unroll
  for (int e = 0; e < 8; e++) {
    float v = src[e];
    _Float16 h = (_Float16)v;
    dh[e] = h;
    dl[e] = (_Float16)(v - (float)h);
  }
}

extern "C" void kernel_launch(void* const* d_in, const int* in_sizes, int n_in,
                              void* d_out, int out_size, void* d_ws, size_t ws_size,
                              hipStream_t stream)
{
  const float* input = (const float*)d_in[0];
  const float* W_in  = (const float*)d_in[1];
  const float* b_in  = (const float*)d_in[2];
  const float* W_h   = (const float*)d_in[3];
  const float* b_h   = (const float*)d_in[4];
  const float* W_out = (const float*)d_in[5];
  const float* b_out = (const float*)d_in[6];
  const float* m_in  = (const float*)d_in[7];
  const float* m_h   = (const float*)d_in[8];
  const float* m_out = (const float*)d_in[9];
  const int* fid_in  = (const int*)d_in[10];
  const int* fid_h   = (const int*)d_in[11];
  const int* fid_out = (const int*)d_in[12];

  const int X     = in_sizes[2];                 // 512
  const int D_IN  = in_sizes[1] / X;             // 512
  const int Z     = in_sizes[3] / (X * X);       // 4
  const int D_OUT = in_sizes[6];                 // 128
  const long B    = (long)in_sizes[0] / D_IN;    // 65536

  const long n_in_w  = (long)X * D_IN;
  const long n_h_w   = (long)X * X;
  const long n_out_w = (long)D_OUT * X;
  const long w_elems = n_in_w + Z * n_h_w + n_out_w;

  _Float16* Wp_in  = (_Float16*)d_ws;
  _Float16* Wp_h0  = Wp_in + 2 * n_in_w;
  _Float16* Wp_out = Wp_h0 + Z * 2 * n_h_w;
  char* actbase = (char*)(Wp_out + 2 * n_out_w);

  size_t wbytes = 4 * (size_t)w_elems;
  size_t avail  = ws_size > wbytes ? ws_size - wbytes : 0;
  long R = (long)(avail / (8 * (size_t)X));
  R = (R / BM) * BM;
  if (R > B) R = B;
  if (R < BM) R = BM;

  _Float16* bufhi[2];   // hi plane base; lo at + R*X
  bufhi[0] = (_Float16*)actbase;
  bufhi[1] = bufhi[0] + 2 * R * (long)X;

  // pack weights once per call
  {
    long t0 = n_in_w / 8, t1 = n_h_w / 8, t2 = n_out_w / 8;
    pack_w<<<(int)((t0 + 255) / 256), 256, 0, stream>>>(W_in, Wp_in, X, D_IN);
    for (int i = 0; i < Z; i++)
      pack_w<<<(int)((t1 + 255) / 256), 256, 0, stream>>>(
          W_h + (long)i * n_h_w, Wp_h0 + (long)i * 2 * n_h_w, X, X);
    pack_w<<<(int)((t2 + 255) / 256), 256, 0, stream>>>(W_out, Wp_out, D_OUT, X);
  }

  for (long r0 = 0; r0 < B; r0 += R) {
    const long rows = (B - r0 < R) ? (B - r0) : R;
    const long planeAct = rows * (long)X;   // == rows * D_IN here (X == D_IN)

    // layer-0 input -> packed fragment layout
    {
      long total = (rows / 16) * (long)(D_IN / 32) * 64;
      pack_a<<<(int)((total + 255) / 256), 256, 0, stream>>>(
          input + r0 * D_IN, bufhi[0], rows * (long)D_IN, D_IN, total);
    }

    const int nRow  = (int)(rows / BM);
    const int nColH = X / BN;
    dim3 gridH((unsigned)(nRow * nColH));
    gemm_pk_act<<<gridH, 256, 0, stream>>>(bufhi[0], rows * (long)D_IN, Wp_in,
        b_in, fid_in, m_in, X, D_IN, nColH, nRow, bufhi[1], planeAct, nullptr);
    int cur = 1;
    for (int i = 0; i < Z; i++) {
      gemm_pk_act<<<gridH, 256, 0, stream>>>(bufhi[cur], planeAct,
          Wp_h0 + (long)i * 2 * n_h_w,
          b_h + (long)i * X, fid_h + (long)i * X, m_h + (long)i * X, X, X,
          nColH, nRow, bufhi[1 - cur], planeAct, nullptr);
      cur ^= 1;
    }
    const int nColO = D_OUT / BN;   // 1
    dim3 gridO((unsigned)(nRow * nColO));
    gemm_pk_act<<<gridO, 256, 0, stream>>>(bufhi[cur], planeAct, Wp_out,
        b_out, fid_out, m_out, D_OUT, X, nColO, nRow,
        nullptr, 0, (float*)d_out + r0 * (long)D_OUT);
  }
}